// Round 12
// baseline (47.266 us; speedup 1.0000x reference)
//
#include <hip/hip_runtime.h>

// Problem constants (fixed by setup_inputs): lfi [B,A,H,W,C], f_maps [B,H,W,F]
#define BB 4
#define AA 9
#define HH 256
#define WW 256
#define CC 9
#define FF 64

// ---------------------------------------------------------------------------
// Fused stage 1 (disjoint block roles; both bodies are round-11 proven,
// constant-bound + explicitly unrolled loops — the round-2 fusion failure
// was a thread-dependent loop bound defeating unrolling, not fusion per se):
//  blocks [0,256):    hv role (round-11 k_hv v2 verbatim) + per-(b,f) max
//                     via LDS reduce + 64 atomicMax/block into mxb.
//  blocks [256,1280): m role (round-9/11 k_m body verbatim).
// ---------------------------------------------------------------------------
__global__ __launch_bounds__(256) void k_fused(const float* __restrict__ fm,
                                               const float* __restrict__ lfi,
                                               float* __restrict__ hv,
                                               int* __restrict__ mxb,
                                               float* __restrict__ m) {
    const int t = threadIdx.x;
    if (blockIdx.x < 256) {
        // ---- hv role: block per (b, w-quad); 1KB/instr contiguous loads ----
        const int wq = blockIdx.x & 63;   // 64 w-quads per batch
        const int b = blockIdx.x >> 6;
        const int f4 = t & 15;
        const int wsub = (t >> 4) & 3;
        const int hl = t >> 6;            // 0..3
        const int w = wq * 4 + wsub;

        const float4* base = (const float4*)fm +
                             ((size_t)(b * HH + hl) * WW + w) * (FF / 4) + f4;
        const size_t hstep = (size_t)4 * WW * (FF / 4);  // 4 h-rows of float4
        float4 acc = make_float4(0.f, 0.f, 0.f, 0.f);
#pragma unroll 16
        for (int i = 0; i < 64; ++i) {    // h = hl + 4*i
            float4 v = base[i * hstep];
            acc.x += v.x; acc.y += v.y; acc.z += v.z; acc.w += v.w;
        }

        __shared__ float4 sm[4][64];      // [hl][wsub*16+f4]
        __shared__ float4 smw[4][16];     // [wsub][f4] final hv values
        sm[hl][wsub * 16 + f4] = acc;
        __syncthreads();
        if (t < 64) {                     // t = wsub*16 + f4
            const float4 s0 = sm[0][t], s1 = sm[1][t];
            const float4 s2 = sm[2][t], s3 = sm[3][t];
            float4 r;
            r.x = ((s0.x + s1.x) + (s2.x + s3.x)) * (1.0f / HH);
            r.y = ((s0.y + s1.y) + (s2.y + s3.y)) * (1.0f / HH);
            r.z = ((s0.z + s1.z) + (s2.z + s3.z)) * (1.0f / HH);
            r.w = ((s0.w + s1.w) + (s2.w + s3.w)) * (1.0f / HH);
            ((float4*)hv)[(size_t)(b * WW + wq * 4 + (t >> 4)) * (FF / 4) +
                          (t & 15)] = r;
            smw[t >> 4][t & 15] = r;
        }
        __syncthreads();
        if (t < 16) {                     // reduce max over the 4 w, atomicMax
            const float4 a0 = smw[0][t], a1 = smw[1][t];
            const float4 a2 = smw[2][t], a3 = smw[3][t];
            float4 mx;
            mx.x = fmaxf(fmaxf(a0.x, a1.x), fmaxf(a2.x, a3.x));
            mx.y = fmaxf(fmaxf(a0.y, a1.y), fmaxf(a2.y, a3.y));
            mx.z = fmaxf(fmaxf(a0.z, a1.z), fmaxf(a2.z, a3.z));
            mx.w = fmaxf(fmaxf(a0.w, a1.w), fmaxf(a2.w, a3.w));
            int* mp = mxb + b * FF + t * 4;
            atomicMax(mp + 0, __float_as_int(mx.x));  // positive floats:
            atomicMax(mp + 1, __float_as_int(mx.y));  // int order == float order
            atomicMax(mp + 2, __float_as_int(mx.z));
            atomicMax(mp + 3, __float_as_int(mx.w));
        }
    } else {
        // ---- m role: round-9 body verbatim ----
        const int blkm = blockIdx.x - 256;   // 0..1023
        const int k = blkm * 256 + t;        // b*65536 + h*256 + w
        const int b = k >> 16;               // HH*WW == 65536
        const int blk_local = blkm & 255;
        const int r = t & 3;                 // window start within 12 floats
        const size_t astride4 = (size_t)HH * WW * CC / 4;  // 147456 float4

        const float4* base = (const float4*)lfi + (size_t)b * AA * astride4 +
                             (size_t)blk_local * 576 + ((9 * t) >> 2);
        float acc = 0.f;
#pragma unroll 3
        for (int a = 0; a < AA; ++a) {
            const float4* p = base + (size_t)a * astride4;
            const float4 v0 = p[0], v1 = p[1], v2 = p[2];
            // w0..w11 = v0.xyzw v1.xyzw v2.xyzw; want sum of w[r..r+8]
            const float s12 = ((v0.x + v0.y) + (v0.z + v0.w)) +
                              ((v1.x + v1.y) + (v1.z + v1.w)) +
                              ((v2.x + v2.y) + (v2.z + v2.w));
            const float head = (r > 0 ? v0.x : 0.f) + (r > 1 ? v0.y : 0.f) +
                               (r > 2 ? v0.z : 0.f);
            const float tail = (r < 1 ? v2.y : 0.f) + (r < 2 ? v2.z : 0.f) +
                               (r < 3 ? v2.w : 0.f);
            acc += s12 - head - tail;
        }
        m[k] = acc * (1.0f / (AA * CC));
    }
}

// ---------------------------------------------------------------------------
// Kernel 2: out[b,h,w,f] = m[b,h,w] * hv[b,h,f] * rcp(max[b,f])
// One thread per float4 along f; contiguous 16B/lane stores. rcp rel err
// ~1e-7 << 1e-2 threshold (proven rounds 4/6/7).
// ---------------------------------------------------------------------------
__global__ __launch_bounds__(256) void k_out(const float* __restrict__ m,
                                             const float* __restrict__ hv,
                                             const int* __restrict__ mxb,
                                             float4* __restrict__ out) {
    const int idx = blockIdx.x * 256 + threadIdx.x;  // over B*H*W*F/4
    const int f4 = idx & 15;                         // FF/4 == 16
    const int rest = idx >> 4;                       // b*HH*WW + h*WW + w
    const int h = (rest >> 8) & 255;
    const int b = rest >> 16;

    const float mv = m[rest];
    const float4 hv4 = ((const float4*)hv)[((size_t)(b * HH + h)) * (FF / 4) + f4];
    const int4 mx4 = ((const int4*)mxb)[b * (FF / 4) + f4];

    float4 o;
    o.x = mv * hv4.x * __builtin_amdgcn_rcpf(__int_as_float(mx4.x));
    o.y = mv * hv4.y * __builtin_amdgcn_rcpf(__int_as_float(mx4.y));
    o.z = mv * hv4.z * __builtin_amdgcn_rcpf(__int_as_float(mx4.z));
    o.w = mv * hv4.w * __builtin_amdgcn_rcpf(__int_as_float(mx4.w));
    out[idx] = o;
}

extern "C" void kernel_launch(void* const* d_in, const int* in_sizes, int n_in,
                              void* d_out, int out_size, void* d_ws, size_t ws_size,
                              hipStream_t stream) {
    const float* lfi = (const float*)d_in[0];  // [B,A,H,W,C] f32
    const float* fm  = (const float*)d_in[1];  // [B,H,W,F]   f32
    float* out = (float*)d_out;                // [B,H,W,F]   f32

    // Workspace layout: hv 256KB | mxb 1KB (pad 4KB) | m 1MB
    char* ws = (char*)d_ws;
    float* hv = (float*)ws;
    int* mxb  = (int*)(ws + (size_t)BB * WW * FF * 4);
    float* m  = (float*)(ws + (size_t)BB * WW * FF * 4 + 4096);

    // 0) zero the atomic-max buffer (re-zeroed every call -> deterministic)
    hipMemsetAsync(mxb, 0, BB * FF * sizeof(int), stream);
    // 1) fused: column means of f_maps (+max) and angular mean of lfi
    k_fused<<<256 + 1024, 256, 0, stream>>>(fm, lfi, hv, mxb, m);
    // 2) broadcast-multiply into out
    k_out<<<(BB * HH * WW * FF / 4) / 256, 256, 0, stream>>>(m, hv, mxb,
                                                             (float4*)out);
}

// Round 13
// 42.481 us; speedup vs baseline: 1.1126x; 1.1126x over previous
//
#include <hip/hip_runtime.h>

// Problem constants (fixed by setup_inputs): lfi [B,A,H,W,C], f_maps [B,H,W,F]
#define BB 4
#define AA 9
#define HH 256
#define WW 256
#define CC 9
#define FF 64

// ---------------------------------------------------------------------------
// Kernel 1 (round-11 body; launch_bounds(256,1) lifts the VGPR cap so the
// unroll-16 float4 flight actually stays in flight):
// hv[b,w,f] = mean_h f_maps[b,h,w,f]. Block per (b, w-quad): 256 threads =
// 4 h-lanes x 4 w x 16 f4; every load instruction = 1KB contiguous.
// ---------------------------------------------------------------------------
__global__ __launch_bounds__(256, 1) void k_hv(const float* __restrict__ fm,
                                               float* __restrict__ hv) {
    const int t = threadIdx.x;
    const int wq = blockIdx.x & 63;   // 64 w-quads per batch
    const int b = blockIdx.x >> 6;
    const int f4 = t & 15;
    const int wsub = (t >> 4) & 3;
    const int hl = t >> 6;            // 0..3
    const int w = wq * 4 + wsub;

    const float4* base = (const float4*)fm +
                         ((size_t)(b * HH + hl) * WW + w) * (FF / 4) + f4;
    const size_t hstep = (size_t)4 * WW * (FF / 4);  // 4 h-rows of float4
    float4 acc = make_float4(0.f, 0.f, 0.f, 0.f);
#pragma unroll 16
    for (int i = 0; i < 64; ++i) {    // h = hl + 4*i
        float4 v = base[i * hstep];
        acc.x += v.x; acc.y += v.y; acc.z += v.z; acc.w += v.w;
    }

    __shared__ float4 sm[4][64];      // [hl][wsub*16+f4]
    sm[hl][wsub * 16 + f4] = acc;
    __syncthreads();
    if (t < 64) {                     // t = wsub*16 + f4
        const float4 s0 = sm[0][t], s1 = sm[1][t], s2 = sm[2][t], s3 = sm[3][t];
        float4 r;
        r.x = ((s0.x + s1.x) + (s2.x + s3.x)) * (1.0f / HH);
        r.y = ((s0.y + s1.y) + (s2.y + s3.y)) * (1.0f / HH);
        r.z = ((s0.z + s1.z) + (s2.z + s3.z)) * (1.0f / HH);
        r.w = ((s0.w + s1.w) + (s2.w + s3.w)) * (1.0f / HH);
        ((float4*)hv)[(size_t)(b * WW + wq * 4 + (t >> 4)) * (FF / 4) + (t & 15)] = r;
    }
}

// ---------------------------------------------------------------------------
// Kernel 2 (round-11 body; launch_bounds(256,1) so the 9-float4 window
// flight gets registers): m[b,h,w] = mean_{a,c} lfi[b,a,h,w,c]
// + inv rider blocks (round-1 k_inv body as 4 waves/block over 64 blocks).
// ---------------------------------------------------------------------------
__global__ __launch_bounds__(256, 1) void k_m(const float* __restrict__ lfi,
                                              const float* __restrict__ hv,
                                              float* __restrict__ m,
                                              float* __restrict__ inv) {
    const int t = threadIdx.x;
    if (blockIdx.x < 1024) {
        const int k = blockIdx.x * 256 + t;  // b*65536 + h*256 + w
        const int b = k >> 16;               // HH*WW == 65536
        const int blk_local = blockIdx.x & 255;
        const int r = t & 3;                 // window start within 12 floats
        const size_t astride4 = (size_t)HH * WW * CC / 4;  // 147456 float4

        const float4* base = (const float4*)lfi + (size_t)b * AA * astride4 +
                             (size_t)blk_local * 576 + ((9 * t) >> 2);
        float acc = 0.f;
#pragma unroll 3
        for (int a = 0; a < AA; ++a) {
            const float4* p = base + (size_t)a * astride4;
            const float4 v0 = p[0], v1 = p[1], v2 = p[2];
            // w0..w11 = v0.xyzw v1.xyzw v2.xyzw; want sum of w[r..r+8]
            const float s12 = ((v0.x + v0.y) + (v0.z + v0.w)) +
                              ((v1.x + v1.y) + (v1.z + v1.w)) +
                              ((v2.x + v2.y) + (v2.z + v2.w));
            const float head = (r > 0 ? v0.x : 0.f) + (r > 1 ? v0.y : 0.f) +
                               (r > 2 ? v0.z : 0.f);
            const float tail = (r < 1 ? v2.y : 0.f) + (r < 2 ? v2.z : 0.f) +
                               (r < 3 ? v2.w : 0.f);
            acc += s12 - head - tail;
        }
        m[k] = acc * (1.0f / (AA * CC));
    } else {
        // inv role: wave = one (b,f) pair, round-1 k_inv body verbatim
        const int rb = blockIdx.x - 1024;    // 0..63
        const int wave = t >> 6;             // 0..3
        const int lane = t & 63;
        const int pair = rb * 4 + wave;      // 0..255
        const int b = pair >> 6;
        const int f = pair & 63;
        float mx = -1e30f;
#pragma unroll
        for (int j = 0; j < 4; ++j) {
            mx = fmaxf(mx, hv[((size_t)b * WW + (lane + 64 * j)) * FF + f]);
        }
#pragma unroll
        for (int off = 32; off; off >>= 1)
            mx = fmaxf(mx, __shfl_xor(mx, off));
        if (lane == 0) inv[pair] = 1.0f / mx;
    }
}

// ---------------------------------------------------------------------------
// Kernel 3 (round-11 verbatim, proven): out = m * hv[b,h,f] * inv[b,f]
// One thread per float4 along f; contiguous 16B/lane stores.
// ---------------------------------------------------------------------------
__global__ __launch_bounds__(256) void k_out(const float* __restrict__ m,
                                             const float* __restrict__ hv,
                                             const float* __restrict__ inv,
                                             float4* __restrict__ out) {
    const int idx = blockIdx.x * 256 + threadIdx.x;  // over B*H*W*F/4
    const int f4 = idx & 15;                         // FF/4 == 16
    const int rest = idx >> 4;                       // b*HH*WW + h*WW + w
    const int h = (rest >> 8) & 255;
    const int b = rest >> 16;

    const float mv = m[rest];
    const float4 hv4 = ((const float4*)hv)[((size_t)(b * HH + h)) * (FF / 4) + f4];
    const float4 iv4 = ((const float4*)inv)[b * (FF / 4) + f4];

    float4 o;
    o.x = mv * hv4.x * iv4.x;
    o.y = mv * hv4.y * iv4.y;
    o.z = mv * hv4.z * iv4.z;
    o.w = mv * hv4.w * iv4.w;
    out[idx] = o;
}

extern "C" void kernel_launch(void* const* d_in, const int* in_sizes, int n_in,
                              void* d_out, int out_size, void* d_ws, size_t ws_size,
                              hipStream_t stream) {
    const float* lfi = (const float*)d_in[0];  // [B,A,H,W,C] f32
    const float* fm  = (const float*)d_in[1];  // [B,H,W,F]   f32
    float* out = (float*)d_out;                // [B,H,W,F]   f32

    // Workspace layout (as round 1): hv 256KB | inv 1KB | m 1MB
    char* ws = (char*)d_ws;
    float* hv  = (float*)ws;
    float* inv = (float*)(ws + (size_t)BB * WW * FF * 4);
    float* m   = (float*)(ws + (size_t)BB * WW * FF * 4 + 1024);

    // 1) column means of f_maps (1KB/instr contiguous, deep ILP)
    k_hv<<<BB * 64, 256, 0, stream>>>(fm, hv);
    // 2) angular mean of lfi + inv rider blocks
    k_m<<<1024 + 64, 256, 0, stream>>>(lfi, hv, m, inv);
    // 3) broadcast-multiply into out
    k_out<<<(BB * HH * WW * FF / 4) / 256, 256, 0, stream>>>(m, hv, inv,
                                                             (float4*)out);
}